// Round 15
// baseline (389.957 us; speedup 1.0000x reference)
//
#include <hip/hip_runtime.h>
#include <math.h>

#define LTOT 131072

typedef unsigned short u16;
typedef unsigned int   u32;
typedef __attribute__((ext_vector_type(8))) short bf16x8;
typedef __attribute__((ext_vector_type(4))) short bf16x4;
typedef __attribute__((ext_vector_type(4))) float f32x4;

__device__ __forceinline__ u16 f2b(float f) {
  union { float f; u32 u; } v; v.f = f;
  u32 r = v.u + 0x7fffu + ((v.u >> 16) & 1u);
  return (u16)(r >> 16);
}

// NOTE: v_cvt_pk_bf16_f32 is NOT RTNE (R3 post-mortem). Softmax P / attT
// only; f2b (RTNE) for anything entering a K=256 dot.
__device__ __forceinline__ u32 cvt_pk(float lo, float hi) {
  u32 r;
  asm("v_cvt_pk_bf16_f32 %0, %1, %2" : "=v"(r) : "v"(lo), "v"(hi));
  return r;
}

__device__ __forceinline__ bf16x8 pack_bp(const f32x4 a, const f32x4 b) {
  union { u32 w[4]; bf16x8 v; } u;
  u.w[0] = cvt_pk(a[0], a[1]);
  u.w[1] = cvt_pk(a[2], a[3]);
  u.w[2] = cvt_pk(b[0], b[1]);
  u.w[3] = cvt_pk(b[2], b[3]);
  return u.v;
}

// =========================================================================
// Kernel 0: one-time weight conversion f32 -> bf16 (RTNE).
//   WB layout (u16): [0) WqB | [32768) WkB | [65536) WvB | [98304) WoB
// =========================================================================
__global__ __launch_bounds__(256) void k_prep(
    const float* __restrict__ Wq, const float* __restrict__ Wk,
    const float* __restrict__ Wv, const float* __restrict__ Wo,
    u16* __restrict__ WB)
{
  for (int idx = blockIdx.x * 256 + threadIdx.x; idx < 131072;
       idx += gridDim.x * 256) {
    int sel = idx >> 15, off = idx & 32767;
    const float* s = (sel == 0) ? Wq : (sel == 1) ? Wk : (sel == 2) ? Wv : Wo;
    WB[idx] = f2b(s[off]);
  }
}

// =========================================================================
// Kernel 1: QKV projection — weights read as bf16 from WB (R14-proven).
// =========================================================================
__device__ __forceinline__ int sxt_addr(int row, int g) {
  return (row << 8) + (((g) ^ (row & 7)) << 3);
}

__global__ __launch_bounds__(512) void k_qkv(
    const float* __restrict__ x1,
    const u16* __restrict__ WB,
    const float* __restrict__ bq, const float* __restrict__ bk,
    const float* __restrict__ bv,
    u16* __restrict__ scratch)
{
  __shared__ __align__(16) u16 sXT[128 * 256];   // [l][k] swizzled, 64 KiB

  const int tid  = threadIdx.x;
  const int lane = tid & 63;
  const int wv   = tid >> 6;        // 8 waves
  const int lr   = lane & 15;
  const int lg   = lane >> 4;
  const int l0   = blockIdx.x << 7;

  {
    const int cl = (tid & 63) << 1;
    const int kq = tid >> 6;
#pragma unroll
    for (int k8 = 0; k8 < 4; ++k8) {
      const int k0 = kq * 32 + k8 * 8;
      float2 v[8];
#pragma unroll
      for (int j = 0; j < 8; ++j)
        v[j] = *reinterpret_cast<const float2*>(x1 + (size_t)(k0 + j) * LTOT + l0 + cl);
      union { u16 h[8]; bf16x8 b; } p0, p1;
#pragma unroll
      for (int j = 0; j < 8; ++j) {
        p0.h[j] = f2b(v[j].x);
        p1.h[j] = f2b(v[j].y);
      }
      const int g = k0 >> 3;
      *reinterpret_cast<bf16x8*>(&sXT[sxt_addr(cl,     g)]) = p0.b;
      *reinterpret_cast<bf16x8*>(&sXT[sxt_addr(cl + 1, g)]) = p1.b;
    }
  }
  __syncthreads();

  const float rs = 0.1275174468f;   // log2(e)/sqrt(128)

#pragma unroll
  for (int wb = 0; wb < 2; ++wb) {
    const u16* Wsel = WB + wb * 32768;
    const float* bsel = wb ? bk : bq;
    const int c = (wv << 4) + lr;

    bf16x8 bw[8];
#pragma unroll
    for (int kc = 0; kc < 8; ++kc)
      bw[kc] = *reinterpret_cast<const bf16x8*>(
          Wsel + (size_t)c * 256 + kc * 32 + (lg << 3));

    f32x4 acc[8];
#pragma unroll
    for (int mt = 0; mt < 8; ++mt) acc[mt] = (f32x4){0.f, 0.f, 0.f, 0.f};
#pragma unroll
    for (int kc = 0; kc < 8; ++kc) {
      const int g = (kc << 2) + lg;
#pragma unroll
      for (int mt = 0; mt < 8; ++mt) {
        bf16x8 a = *reinterpret_cast<const bf16x8*>(&sXT[sxt_addr((mt << 4) + lr, g)]);
        acc[mt] = __builtin_amdgcn_mfma_f32_16x16x32_bf16(bw[kc], a, acc[mt], 0, 0, 0);
      }
    }

    const int c0 = (wv << 4) + (lg << 2);
    float4 b4 = *reinterpret_cast<const float4*>(bsel + c0);
    const float bb[4] = {b4.x, b4.y, b4.z, b4.w};
    const float scale = wb ? 1.f : rs;
    u16* dst = scratch + (size_t)wb * 128 * LTOT;
#pragma unroll
    for (int mt = 0; mt < 8; ++mt) {
      const int l = l0 + (mt << 4) + lr;
      union { u16 h[4]; uint2 v; } s;
#pragma unroll
      for (int r = 0; r < 4; ++r)
        s.h[r] = f2b((acc[mt][r] + bb[r]) * scale);
      *reinterpret_cast<uint2*>(dst + (size_t)l * 128 + c0) = s.v;
    }
  }

  {
    const u16* Wsel = WB + 65536;
    const int c = (wv << 4) + lr;
    bf16x8 aw[8];
#pragma unroll
    for (int kc = 0; kc < 8; ++kc)
      aw[kc] = *reinterpret_cast<const bf16x8*>(
          Wsel + (size_t)c * 256 + kc * 32 + (lg << 3));

    f32x4 acc[8];
#pragma unroll
    for (int nt = 0; nt < 8; ++nt) acc[nt] = (f32x4){0.f, 0.f, 0.f, 0.f};
#pragma unroll
    for (int kc = 0; kc < 8; ++kc) {
      const int g = (kc << 2) + lg;
#pragma unroll
      for (int nt = 0; nt < 8; ++nt) {
        bf16x8 b = *reinterpret_cast<const bf16x8*>(&sXT[sxt_addr((nt << 4) + lr, g)]);
        acc[nt] = __builtin_amdgcn_mfma_f32_16x16x32_bf16(b, aw[kc], acc[nt], 0, 0, 0);
      }
    }

    const float bias = bv[c];
    u16* dstv = scratch + (size_t)256 * LTOT + (size_t)c * LTOT;
#pragma unroll
    for (int nt = 0; nt < 8; ++nt) {
      const int p0 = l0 + (nt << 4) + (lg << 2);
      union { u16 h[4]; uint2 v; } s;
#pragma unroll
      for (int r = 0; r < 4; ++r)
        s.h[r] = f2b(acc[nt][r] + bias);
      *reinterpret_cast<uint2*>(dstv + p0) = s.v;
    }
  }
}

// =========================================================================
// Kernel 2: sliding-window attention — R10/R14 loop + sClean softmax skip.
// STAGING LOOP BYTE-IDENTICAL to R10/R14 (no interior wrapper — that was
// the R5/R7 830MB-FETCH culprit; sClean alone was benign in R6).
// Clean tiles (all fm==1): skip table reads, lf-add, fm-mul.
// =========================================================================
__global__ __launch_bounds__(256, 2) void k_attn(
    const u16* __restrict__ scratch,
    const float* __restrict__ mask,
    u16* __restrict__ attT)
{
  __shared__ __align__(16) unsigned char smem[44096];
  u16*   sKT = (u16*)smem;               // [64][136]  17408 B
  u16*   sV  = (u16*)(smem + 17408);     // [128][72]  18432 B
  float* sLF = (float*)(smem + 35840);   // [1024] log2(fm+1e-6)
  float* sFM = (float*)(smem + 39936);   // [1024] fm
  u32*   sClean = (u32*)(smem + 44032);  // [16] all-fm==1 flags

  const int tid  = threadIdx.x;
  const int lane = tid & 63;
  const int wv   = tid >> 6;                 // 4 waves
  const int lr   = lane & 15;
  const int lg   = lane >> 4;
  const int lid  = ((int)blockIdx.x & 7) * 128 + ((int)blockIdx.x >> 3);
  const int lq0  = lid << 7;                 // 128 queries / WG
  const int p_base = (lq0 >> 9) * 512 - 256;
  const int wq0  = lq0 + wv * 32;            // 32 queries / wave

  const u16* QT = scratch;
  const u16* KT = scratch + (size_t)128 * LTOT;
  const u16* Vp = scratch + (size_t)256 * LTOT;

  if (tid < 16) sClean[tid] = 1u;
  __syncthreads();
  for (int idx = tid; idx < 1024; idx += 256) {
    int p = p_base + idx;
    float fmv = 0.f;
    if (idx < 1023 && (unsigned)p < (unsigned)LTOT) fmv = mask[p];
    sFM[idx] = fmv;
    sLF[idx] = log2f(fmv + 1e-6f);
    if (fmv != 1.0f) sClean[idx >> 6] = 0u;
  }

  bf16x8 aQ0[4], aQ1[4];
#pragma unroll
  for (int kc = 0; kc < 4; ++kc) {
    aQ0[kc] = *reinterpret_cast<const bf16x8*>(
        QT + (size_t)(wq0 + lr) * 128 + kc * 32 + (lg << 3));
    aQ1[kc] = *reinterpret_cast<const bf16x8*>(
        QT + (size_t)(wq0 + 16 + lr) * 128 + kc * 32 + (lg << 3));
  }

  float m0 = -INFINITY, m1 = -INFINITY;
  f32x4 d40 = (f32x4){0.f, 0.f, 0.f, 0.f};
  f32x4 d41 = (f32x4){0.f, 0.f, 0.f, 0.f};
  f32x4 accO0[8], accO1[8];
#pragma unroll
  for (int cm = 0; cm < 8; ++cm) {
    accO0[cm] = (f32x4){0.f, 0.f, 0.f, 0.f};
    accO1[cm] = (f32x4){0.f, 0.f, 0.f, 0.f};
  }

  uint4 rk[4], rv[4];
  {
    const int p0 = p_base;
#pragma unroll
    for (int j = 0; j < 4; ++j) {
      int idx = tid + j * 256;
      int row = idx >> 4, ch = (idx & 15) << 3;
      int p = p0 + row;
      rk[j] = make_uint4(0u, 0u, 0u, 0u);
      if ((unsigned)p < (unsigned)LTOT)
        rk[j] = *reinterpret_cast<const uint4*>(KT + (size_t)p * 128 + ch);
      int c = idx >> 3, w = (idx & 7) << 3;
      int pp = p0 + w;
      rv[j] = make_uint4(0u, 0u, 0u, 0u);
      if ((unsigned)pp < (unsigned)LTOT)
        rv[j] = *reinterpret_cast<const uint4*>(Vp + (size_t)c * LTOT + pp);
    }
  }
#pragma unroll
  for (int j = 0; j < 4; ++j) {
    int idx = tid + j * 256;
    int row = idx >> 4, ch = (idx & 15) << 3;
    *reinterpret_cast<uint4*>(&sKT[row * 136 + ch]) = rk[j];
    int c = idx >> 3, w = (idx & 7) << 3;
    *reinterpret_cast<uint4*>(&sV[c * 72 + w]) = rv[j];
  }
  __syncthreads();

  for (int it = 0; it < 16; ++it) {
    if (it < 15) {
      const int p0 = p_base + (it + 1) * 64;
#pragma unroll
      for (int j = 0; j < 4; ++j) {
        int idx = tid + j * 256;
        int row = idx >> 4, ch = (idx & 15) << 3;
        int p = p0 + row;
        rk[j] = make_uint4(0u, 0u, 0u, 0u);
        if ((unsigned)p < (unsigned)LTOT)
          rk[j] = *reinterpret_cast<const uint4*>(KT + (size_t)p * 128 + ch);
        int c = idx >> 3, w = (idx & 7) << 3;
        int pp = p0 + w;
        rv[j] = make_uint4(0u, 0u, 0u, 0u);
        if ((unsigned)pp < (unsigned)LTOT)
          rv[j] = *reinterpret_cast<const uint4*>(Vp + (size_t)c * LTOT + pp);
      }
    }

    f32x4 e0[4], e1[4];
#pragma unroll
    for (int nt = 0; nt < 4; ++nt) {
      e0[nt] = (f32x4){0.f, 0.f, 0.f, 0.f};
      e1[nt] = (f32x4){0.f, 0.f, 0.f, 0.f};
    }
#pragma unroll
    for (int kc = 0; kc < 4; ++kc) {
      const int ko = kc * 32 + (lg << 3);
#pragma unroll
      for (int nt = 0; nt < 4; ++nt) {
        bf16x8 bk = *reinterpret_cast<const bf16x8*>(&sKT[(nt * 16 + lr) * 136 + ko]);
        e0[nt] = __builtin_amdgcn_mfma_f32_16x16x32_bf16(bk, aQ0[kc], e0[nt], 0, 0, 0);
        e1[nt] = __builtin_amdgcn_mfma_f32_16x16x32_bf16(bk, aQ1[kc], e1[nt], 0, 0, 0);
      }
    }

    const int wbase = it * 64 + (lg << 2);
    const bool clean = (sClean[it] != 0u);
    bf16x8 bpA0, bpA1, bpB0, bpB1;

    if (clean) {
      // all fm==1: no lf add, no fm mul, no table reads (R6-validated)
      {
        float lmax = e0[0][0];
#pragma unroll
        for (int nt = 0; nt < 4; ++nt)
#pragma unroll
          for (int r = 0; r < 4; ++r) if (nt || r) lmax = fmaxf(lmax, e0[nt][r]);
        if (__any(lmax > m0 + 12.0f)) {
          float rmax = lmax;
          rmax = fmaxf(rmax, __shfl_xor(rmax, 16));
          rmax = fmaxf(rmax, __shfl_xor(rmax, 32));
          float mnew = fmaxf(m0, rmax);
          float fs = exp2f(m0 - mnew);
          d40 *= fs;
#pragma unroll
          for (int cm = 0; cm < 8; ++cm) accO0[cm] *= fs;
          m0 = mnew;
        }
        f32x4 pd[4];
#pragma unroll
        for (int nt = 0; nt < 4; ++nt) {
#pragma unroll
          for (int r = 0; r < 4; ++r) pd[nt][r] = exp2f(e0[nt][r] - m0);
          d40 += pd[nt];
        }
        bpA0 = pack_bp(pd[0], pd[1]);
        bpA1 = pack_bp(pd[2], pd[3]);
      }
      {
        float lmax = e1[0][0];
#pragma unroll
        for (int nt = 0; nt < 4; ++nt)
#pragma unroll
          for (int r = 0; r < 4; ++r) if (nt || r) lmax = fmaxf(lmax, e1[nt][r]);
        if (__any(lmax > m1 + 12.0f)) {
          float rmax = lmax;
          rmax = fmaxf(rmax, __shfl_xor(rmax, 16));
          rmax = fmaxf(rmax, __shfl_xor(rmax, 32));
          float mnew = fmaxf(m1, rmax);
          float fs = exp2f(m1 - mnew);
          d41 *= fs;
#pragma unroll
          for (int cm = 0; cm < 8; ++cm) accO1[cm] *= fs;
          m1 = mnew;
        }
        f32x4 pd[4];
#pragma unroll
        for (int nt = 0; nt < 4; ++nt) {
#pragma unroll
          for (int r = 0; r < 4; ++r) pd[nt][r] = exp2f(e1[nt][r] - m1);
          d41 += pd[nt];
        }
        bpB0 = pack_bp(pd[0], pd[1]);
        bpB1 = pack_bp(pd[2], pd[3]);
      }
    } else {
      f32x4 lf[4], fmv[4];
#pragma unroll
      for (int nt = 0; nt < 4; ++nt) {
        lf[nt]  = *reinterpret_cast<const f32x4*>(&sLF[wbase + nt * 16]);
        fmv[nt] = *reinterpret_cast<const f32x4*>(&sFM[wbase + nt * 16]);
        e0[nt] += lf[nt];
        e1[nt] += lf[nt];
      }
      {
        float lmax = e0[0][0];
#pragma unroll
        for (int nt = 0; nt < 4; ++nt)
#pragma unroll
          for (int r = 0; r < 4; ++r) if (nt || r) lmax = fmaxf(lmax, e0[nt][r]);
        if (__any(lmax > m0 + 12.0f)) {
          float rmax = lmax;
          rmax = fmaxf(rmax, __shfl_xor(rmax, 16));
          rmax = fmaxf(rmax, __shfl_xor(rmax, 32));
          float mnew = fmaxf(m0, rmax);
          float fs = exp2f(m0 - mnew);
          d40 *= fs;
#pragma unroll
          for (int cm = 0; cm < 8; ++cm) accO0[cm] *= fs;
          m0 = mnew;
        }
        f32x4 pn[4];
#pragma unroll
        for (int nt = 0; nt < 4; ++nt) {
          f32x4 pd;
#pragma unroll
          for (int r = 0; r < 4; ++r) pd[r] = exp2f(e0[nt][r] - m0);
          d40 += pd;
          pn[nt] = pd * fmv[nt];
        }
        bpA0 = pack_bp(pn[0], pn[1]);
        bpA1 = pack_bp(pn[2], pn[3]);
      }
      {
        float lmax = e1[0][0];
#pragma unroll
        for (int nt = 0; nt < 4; ++nt)
#pragma unroll
          for (int r = 0; r < 4; ++r) if (nt || r) lmax = fmaxf(lmax, e1[nt][r]);
        if (__any(lmax > m1 + 12.0f)) {
          float rmax = lmax;
          rmax = fmaxf(rmax, __shfl_xor(rmax, 16));
          rmax = fmaxf(rmax, __shfl_xor(rmax, 32));
          float mnew = fmaxf(m1, rmax);
          float fs = exp2f(m1 - mnew);
          d41 *= fs;
#pragma unroll
          for (int cm = 0; cm < 8; ++cm) accO1[cm] *= fs;
          m1 = mnew;
        }
        f32x4 pn[4];
#pragma unroll
        for (int nt = 0; nt < 4; ++nt) {
          f32x4 pd;
#pragma unroll
          for (int r = 0; r < 4; ++r) pd[r] = exp2f(e1[nt][r] - m1);
          d41 += pd;
          pn[nt] = pd * fmv[nt];
        }
        bpB0 = pack_bp(pn[0], pn[1]);
        bpB1 = pack_bp(pn[2], pn[3]);
      }
    }

#pragma unroll
    for (int k2 = 0; k2 < 2; ++k2) {
      const bf16x8 pA = k2 ? bpA1 : bpA0;
      const bf16x8 pB = k2 ? bpB1 : bpB0;
      const int vo = k2 * 32 + (lg << 2);
#pragma unroll
      for (int cm = 0; cm < 8; ++cm) {
        const u16* vr = &sV[(cm * 16 + lr) * 72 + vo];
        bf16x4 v0 = *reinterpret_cast<const bf16x4*>(vr);
        bf16x4 v1 = *reinterpret_cast<const bf16x4*>(vr + 16);
        bf16x8 av = __builtin_shufflevector(v0, v1, 0, 1, 2, 3, 4, 5, 6, 7);
        accO0[cm] = __builtin_amdgcn_mfma_f32_16x16x32_bf16(av, pA, accO0[cm], 0, 0, 0);
        accO1[cm] = __builtin_amdgcn_mfma_f32_16x16x32_bf16(av, pB, accO1[cm], 0, 0, 0);
      }
    }

    __syncthreads();
    if (it < 15) {
#pragma unroll
      for (int j = 0; j < 4; ++j) {
        int idx = tid + j * 256;
        int row = idx >> 4, ch = (idx & 15) << 3;
        *reinterpret_cast<uint4*>(&sKT[row * 136 + ch]) = rk[j];
        int c = idx >> 3, w = (idx & 7) << 3;
        *reinterpret_cast<uint4*>(&sV[c * 72 + w]) = rv[j];
      }
    }
    __syncthreads();
  }

  float ds0 = d40[0] + d40[1] + d40[2] + d40[3];
  ds0 += __shfl_xor(ds0, 16);
  ds0 += __shfl_xor(ds0, 32);
  const float rd0 = 1.f / ds0;
  float ds1 = d41[0] + d41[1] + d41[2] + d41[3];
  ds1 += __shfl_xor(ds1, 16);
  ds1 += __shfl_xor(ds1, 32);
  const float rd1 = 1.f / ds1;

  u16* sT = (u16*)smem + wv * 2176;   // per-wave [16][136]
#pragma unroll
  for (int cm = 0; cm < 8; ++cm) {
    float o0 = fmaxf(accO0[cm][0] * rd0, 0.f);
    float o1 = fmaxf(accO0[cm][1] * rd0, 0.f);
    float o2 = fmaxf(accO0[cm][2] * rd0, 0.f);
    float o3 = fmaxf(accO0[cm][3] * rd0, 0.f);
    uint2 pk = make_uint2(cvt_pk(o0, o1), cvt_pk(o2, o3));
    *reinterpret_cast<uint2*>(&sT[lr * 136 + cm * 16 + (lg << 2)]) = pk;
  }
  for (int idx = lane; idx < 256; idx += 64) {
    int row = idx >> 4, ch = (idx & 15) << 3;
    uint4 v = *reinterpret_cast<const uint4*>(&sT[row * 136 + ch]);
    *reinterpret_cast<uint4*>(attT + (size_t)(wq0 + row) * 128 + ch) = v;
  }
#pragma unroll
  for (int cm = 0; cm < 8; ++cm) {
    float o0 = fmaxf(accO1[cm][0] * rd1, 0.f);
    float o1 = fmaxf(accO1[cm][1] * rd1, 0.f);
    float o2 = fmaxf(accO1[cm][2] * rd1, 0.f);
    float o3 = fmaxf(accO1[cm][3] * rd1, 0.f);
    uint2 pk = make_uint2(cvt_pk(o0, o1), cvt_pk(o2, o3));
    *reinterpret_cast<uint2*>(&sT[lr * 136 + cm * 16 + (lg << 2)]) = pk;
  }
  for (int idx = lane; idx < 256; idx += 64) {
    int row = idx >> 4, ch = (idx & 15) << 3;
    uint4 v = *reinterpret_cast<const uint4*>(&sT[row * 136 + ch]);
    *reinterpret_cast<uint4*>(attT + (size_t)(wq0 + 16 + row) * 128 + ch) = v;
  }
}

// =========================================================================
// Kernel 3: out[o][l] = (WoB @ attT^T + bo) * mask — R10-proven version.
// =========================================================================
__device__ __forceinline__ int sa_addr(int row, int g) {
  return (row << 7) + (((g) ^ (row & 7)) << 3);
}

__global__ __launch_bounds__(512) void k_out(
    const u16* __restrict__ attT, const u16* __restrict__ WoB,
    const float* __restrict__ bo, const float* __restrict__ mask,
    float* __restrict__ out)
{
  __shared__ __align__(16) u16 sA[128 * 128];   // [l][c] swizzled, 32 KiB

  const int tid  = threadIdx.x;
  const int lane = tid & 63;
  const int wv   = tid >> 6;        // 8 waves; wave owns 32 o-rows
  const int lr   = lane & 15;
  const int lg   = lane >> 4;
  const int l0   = blockIdx.x << 7;

  for (int idx = tid; idx < 2048; idx += 512) {
    int row = idx >> 4, g = idx & 15;
    uint4 v = *reinterpret_cast<const uint4*>(attT + (size_t)(l0 + row) * 128 + (g << 3));
    *reinterpret_cast<uint4*>(&sA[sa_addr(row, g)]) = v;
  }
  __syncthreads();

  const int ob = wv << 5;
  f32x4 acc[2][8];
#pragma unroll
  for (int mt = 0; mt < 2; ++mt)
#pragma unroll
    for (int nt = 0; nt < 8; ++nt) acc[mt][nt] = (f32x4){0.f, 0.f, 0.f, 0.f};

#pragma unroll
  for (int kc = 0; kc < 4; ++kc) {
    bf16x8 a[2], b[8];
#pragma unroll
    for (int mt = 0; mt < 2; ++mt)
      a[mt] = *reinterpret_cast<const bf16x8*>(
          WoB + (size_t)(ob + mt * 16 + lr) * 128 + kc * 32 + (lg << 3));
    const int g = (kc << 2) + lg;
#pragma unroll
    for (int nt = 0; nt < 8; ++nt)
      b[nt] = *reinterpret_cast<const bf16x8*>(&sA[sa_addr(nt * 16 + lr, g)]);
#pragma unroll
    for (int mt = 0; mt < 2; ++mt)
#pragma unroll
      for (int nt = 0; nt < 8; ++nt)
        acc[mt][nt] = __builtin_amdgcn_mfma_f32_16x16x32_bf16(a[mt], b[nt], acc[mt][nt], 0, 0, 0);
  }

#pragma unroll
  for (int mt = 0; mt < 2; ++mt) {
    const int o0 = ob + mt * 16 + (lg << 2);
    float4 b4 = *reinterpret_cast<const float4*>(bo + o0);
#pragma unroll
    for (int nt = 0; nt < 8; ++nt) {
      const int l = l0 + nt * 16 + lr;
      const float mk = mask[l];
      out[(size_t)(o0 + 0) * LTOT + l] = (acc[mt][nt][0] + b4.x) * mk;
      out[(size_t)(o0 + 1) * LTOT + l] = (acc[mt][nt][1] + b4.y) * mk;
      out[(size_t)(o0 + 2) * LTOT + l] = (acc[mt][nt][2] + b4.z) * mk;
      out[(size_t)(o0 + 3) * LTOT + l] = (acc[mt][nt][3] + b4.w) * mk;
    }
  }
}

extern "C" void kernel_launch(void* const* d_in, const int* in_sizes, int n_in,
                              void* d_out, int out_size, void* d_ws, size_t ws_size,
                              hipStream_t stream) {
  (void)in_sizes; (void)n_in; (void)out_size; (void)ws_size;
  const float* x1   = (const float*)d_in[0];
  const float* mask = (const float*)d_in[1];
  const float* Wq   = (const float*)d_in[2];
  const float* bq   = (const float*)d_in[3];
  const float* Wk   = (const float*)d_in[4];
  const float* bk   = (const float*)d_in[5];
  const float* Wv   = (const float*)d_in[6];
  const float* bv   = (const float*)d_in[7];
  const float* Wo   = (const float*)d_in[8];
  const float* bo   = (const float*)d_in[9];

  u16* scratch = (u16*)d_out;                // QKV scratch in d_out
  u16* attT    = (u16*)d_ws;                 // 32 MiB
  u16* WB      = attT + (size_t)128 * LTOT;  // +256 KiB weights bf16
  u16* WoB     = WB + 98304;
  float* out   = (float*)d_out;

  hipLaunchKernelGGL(k_prep, dim3(128), dim3(256), 0, stream,
                     Wq, Wk, Wv, Wo, WB);
  hipLaunchKernelGGL(k_qkv, dim3(1024), dim3(512), 0, stream,
                     x1, WB, bq, bk, bv, scratch);
  hipLaunchKernelGGL(k_attn, dim3(1024), dim3(256), 0, stream,
                     scratch, mask, attT);
  hipLaunchKernelGGL(k_out, dim3(1024), dim3(512), 0, stream,
                     attT, WoB, bo, mask, out);
}

// Round 16
// 218.370 us; speedup vs baseline: 1.7858x; 1.7858x over previous
//
#include <hip/hip_runtime.h>
#include <math.h>

#define LTOT 131072

typedef unsigned short u16;
typedef unsigned int   u32;
typedef __attribute__((ext_vector_type(8))) short bf16x8;
typedef __attribute__((ext_vector_type(4))) short bf16x4;
typedef __attribute__((ext_vector_type(4))) float f32x4;

__device__ __forceinline__ u16 f2b(float f) {
  union { float f; u32 u; } v; v.f = f;
  u32 r = v.u + 0x7fffu + ((v.u >> 16) & 1u);
  return (u16)(r >> 16);
}

// NOTE: v_cvt_pk_bf16_f32 is NOT RTNE (R3 post-mortem). Softmax P / attT
// only; f2b (RTNE) for anything entering a K=256 dot.
__device__ __forceinline__ u32 cvt_pk(float lo, float hi) {
  u32 r;
  asm("v_cvt_pk_bf16_f32 %0, %1, %2" : "=v"(r) : "v"(lo), "v"(hi));
  return r;
}

__device__ __forceinline__ bf16x8 pack_bp(const f32x4 a, const f32x4 b) {
  union { u32 w[4]; bf16x8 v; } u;
  u.w[0] = cvt_pk(a[0], a[1]);
  u.w[1] = cvt_pk(a[2], a[3]);
  u.w[2] = cvt_pk(b[0], b[1]);
  u.w[3] = cvt_pk(b[2], b[3]);
  return u.v;
}

// =========================================================================
// Kernel 0: one-time weight conversion f32 -> bf16 (RTNE).
//   WB layout (u16): [0) WqB | [32768) WkB | [65536) WvB | [98304) WoB
// =========================================================================
__global__ __launch_bounds__(256) void k_prep(
    const float* __restrict__ Wq, const float* __restrict__ Wk,
    const float* __restrict__ Wv, const float* __restrict__ Wo,
    u16* __restrict__ WB)
{
  for (int idx = blockIdx.x * 256 + threadIdx.x; idx < 131072;
       idx += gridDim.x * 256) {
    int sel = idx >> 15, off = idx & 32767;
    const float* s = (sel == 0) ? Wq : (sel == 1) ? Wk : (sel == 2) ? Wv : Wo;
    WB[idx] = f2b(s[off]);
  }
}

// =========================================================================
// Kernel 1: QKV projection — weights read as bf16 from WB (R14-proven).
// =========================================================================
__device__ __forceinline__ int sxt_addr(int row, int g) {
  return (row << 8) + (((g) ^ (row & 7)) << 3);
}

__global__ __launch_bounds__(512) void k_qkv(
    const float* __restrict__ x1,
    const u16* __restrict__ WB,
    const float* __restrict__ bq, const float* __restrict__ bk,
    const float* __restrict__ bv,
    u16* __restrict__ scratch)
{
  __shared__ __align__(16) u16 sXT[128 * 256];   // [l][k] swizzled, 64 KiB

  const int tid  = threadIdx.x;
  const int lane = tid & 63;
  const int wv   = tid >> 6;        // 8 waves
  const int lr   = lane & 15;
  const int lg   = lane >> 4;
  const int l0   = blockIdx.x << 7;

  {
    const int cl = (tid & 63) << 1;
    const int kq = tid >> 6;
#pragma unroll
    for (int k8 = 0; k8 < 4; ++k8) {
      const int k0 = kq * 32 + k8 * 8;
      float2 v[8];
#pragma unroll
      for (int j = 0; j < 8; ++j)
        v[j] = *reinterpret_cast<const float2*>(x1 + (size_t)(k0 + j) * LTOT + l0 + cl);
      union { u16 h[8]; bf16x8 b; } p0, p1;
#pragma unroll
      for (int j = 0; j < 8; ++j) {
        p0.h[j] = f2b(v[j].x);
        p1.h[j] = f2b(v[j].y);
      }
      const int g = k0 >> 3;
      *reinterpret_cast<bf16x8*>(&sXT[sxt_addr(cl,     g)]) = p0.b;
      *reinterpret_cast<bf16x8*>(&sXT[sxt_addr(cl + 1, g)]) = p1.b;
    }
  }
  __syncthreads();

  const float rs = 0.1275174468f;   // log2(e)/sqrt(128)

#pragma unroll
  for (int wb = 0; wb < 2; ++wb) {
    const u16* Wsel = WB + wb * 32768;
    const float* bsel = wb ? bk : bq;
    const int c = (wv << 4) + lr;

    bf16x8 bw[8];
#pragma unroll
    for (int kc = 0; kc < 8; ++kc)
      bw[kc] = *reinterpret_cast<const bf16x8*>(
          Wsel + (size_t)c * 256 + kc * 32 + (lg << 3));

    f32x4 acc[8];
#pragma unroll
    for (int mt = 0; mt < 8; ++mt) acc[mt] = (f32x4){0.f, 0.f, 0.f, 0.f};
#pragma unroll
    for (int kc = 0; kc < 8; ++kc) {
      const int g = (kc << 2) + lg;
#pragma unroll
      for (int mt = 0; mt < 8; ++mt) {
        bf16x8 a = *reinterpret_cast<const bf16x8*>(&sXT[sxt_addr((mt << 4) + lr, g)]);
        acc[mt] = __builtin_amdgcn_mfma_f32_16x16x32_bf16(bw[kc], a, acc[mt], 0, 0, 0);
      }
    }

    const int c0 = (wv << 4) + (lg << 2);
    float4 b4 = *reinterpret_cast<const float4*>(bsel + c0);
    const float bb[4] = {b4.x, b4.y, b4.z, b4.w};
    const float scale = wb ? 1.f : rs;
    u16* dst = scratch + (size_t)wb * 128 * LTOT;
#pragma unroll
    for (int mt = 0; mt < 8; ++mt) {
      const int l = l0 + (mt << 4) + lr;
      union { u16 h[4]; uint2 v; } s;
#pragma unroll
      for (int r = 0; r < 4; ++r)
        s.h[r] = f2b((acc[mt][r] + bb[r]) * scale);
      *reinterpret_cast<uint2*>(dst + (size_t)l * 128 + c0) = s.v;
    }
  }

  {
    const u16* Wsel = WB + 65536;
    const int c = (wv << 4) + lr;
    bf16x8 aw[8];
#pragma unroll
    for (int kc = 0; kc < 8; ++kc)
      aw[kc] = *reinterpret_cast<const bf16x8*>(
          Wsel + (size_t)c * 256 + kc * 32 + (lg << 3));

    f32x4 acc[8];
#pragma unroll
    for (int nt = 0; nt < 8; ++nt) acc[nt] = (f32x4){0.f, 0.f, 0.f, 0.f};
#pragma unroll
    for (int kc = 0; kc < 8; ++kc) {
      const int g = (kc << 2) + lg;
#pragma unroll
      for (int nt = 0; nt < 8; ++nt) {
        bf16x8 b = *reinterpret_cast<const bf16x8*>(&sXT[sxt_addr((nt << 4) + lr, g)]);
        acc[nt] = __builtin_amdgcn_mfma_f32_16x16x32_bf16(b, aw[kc], acc[nt], 0, 0, 0);
      }
    }

    const float bias = bv[c];
    u16* dstv = scratch + (size_t)256 * LTOT + (size_t)c * LTOT;
#pragma unroll
    for (int nt = 0; nt < 8; ++nt) {
      const int p0 = l0 + (nt << 4) + (lg << 2);
      union { u16 h[4]; uint2 v; } s;
#pragma unroll
      for (int r = 0; r < 4; ++r)
        s.h[r] = f2b(acc[nt][r] + bias);
      *reinterpret_cast<uint2*>(dstv + p0) = s.v;
    }
  }
}

// =========================================================================
// Kernel 2: sliding-window attention — R10/R14-proven VERBATIM.
// (4 waves x 32 q, fused QK/PV LDS reads, XCD swizzle, branch-free inner
// loop. Rule learned R5/R7/R15: NO branches inside this loop — any
// duplicated-body branch perturbs the staging schedule, 2-3x regression.)
// =========================================================================
__global__ __launch_bounds__(256, 2) void k_attn(
    const u16* __restrict__ scratch,
    const float* __restrict__ mask,
    u16* __restrict__ attT)
{
  __shared__ __align__(16) unsigned char smem[44032];
  u16*   sKT = (u16*)smem;               // [64][136]  17408 B
  u16*   sV  = (u16*)(smem + 17408);     // [128][72]  18432 B
  float* sLF = (float*)(smem + 35840);   // [1024] log2(fm+1e-6)
  float* sFM = (float*)(smem + 39936);   // [1024] fm

  const int tid  = threadIdx.x;
  const int lane = tid & 63;
  const int wv   = tid >> 6;                 // 4 waves
  const int lr   = lane & 15;
  const int lg   = lane >> 4;
  const int lid  = ((int)blockIdx.x & 7) * 128 + ((int)blockIdx.x >> 3);
  const int lq0  = lid << 7;                 // 128 queries / WG
  const int p_base = (lq0 >> 9) * 512 - 256;
  const int wq0  = lq0 + wv * 32;            // 32 queries / wave

  const u16* QT = scratch;
  const u16* KT = scratch + (size_t)128 * LTOT;
  const u16* Vp = scratch + (size_t)256 * LTOT;

  for (int idx = tid; idx < 1024; idx += 256) {
    int p = p_base + idx;
    float fmv = 0.f;
    if (idx < 1023 && (unsigned)p < (unsigned)LTOT) fmv = mask[p];
    sFM[idx] = fmv;
    sLF[idx] = log2f(fmv + 1e-6f);
  }

  bf16x8 aQ0[4], aQ1[4];
#pragma unroll
  for (int kc = 0; kc < 4; ++kc) {
    aQ0[kc] = *reinterpret_cast<const bf16x8*>(
        QT + (size_t)(wq0 + lr) * 128 + kc * 32 + (lg << 3));
    aQ1[kc] = *reinterpret_cast<const bf16x8*>(
        QT + (size_t)(wq0 + 16 + lr) * 128 + kc * 32 + (lg << 3));
  }

  float m0 = -INFINITY, m1 = -INFINITY;
  f32x4 d40 = (f32x4){0.f, 0.f, 0.f, 0.f};
  f32x4 d41 = (f32x4){0.f, 0.f, 0.f, 0.f};
  f32x4 accO0[8], accO1[8];
#pragma unroll
  for (int cm = 0; cm < 8; ++cm) {
    accO0[cm] = (f32x4){0.f, 0.f, 0.f, 0.f};
    accO1[cm] = (f32x4){0.f, 0.f, 0.f, 0.f};
  }

  uint4 rk[4], rv[4];
  {
    const int p0 = p_base;
#pragma unroll
    for (int j = 0; j < 4; ++j) {
      int idx = tid + j * 256;
      int row = idx >> 4, ch = (idx & 15) << 3;
      int p = p0 + row;
      rk[j] = make_uint4(0u, 0u, 0u, 0u);
      if ((unsigned)p < (unsigned)LTOT)
        rk[j] = *reinterpret_cast<const uint4*>(KT + (size_t)p * 128 + ch);
      int c = idx >> 3, w = (idx & 7) << 3;
      int pp = p0 + w;
      rv[j] = make_uint4(0u, 0u, 0u, 0u);
      if ((unsigned)pp < (unsigned)LTOT)
        rv[j] = *reinterpret_cast<const uint4*>(Vp + (size_t)c * LTOT + pp);
    }
  }
#pragma unroll
  for (int j = 0; j < 4; ++j) {
    int idx = tid + j * 256;
    int row = idx >> 4, ch = (idx & 15) << 3;
    *reinterpret_cast<uint4*>(&sKT[row * 136 + ch]) = rk[j];
    int c = idx >> 3, w = (idx & 7) << 3;
    *reinterpret_cast<uint4*>(&sV[c * 72 + w]) = rv[j];
  }
  __syncthreads();

  for (int it = 0; it < 16; ++it) {
    if (it < 15) {
      const int p0 = p_base + (it + 1) * 64;
#pragma unroll
      for (int j = 0; j < 4; ++j) {
        int idx = tid + j * 256;
        int row = idx >> 4, ch = (idx & 15) << 3;
        int p = p0 + row;
        rk[j] = make_uint4(0u, 0u, 0u, 0u);
        if ((unsigned)p < (unsigned)LTOT)
          rk[j] = *reinterpret_cast<const uint4*>(KT + (size_t)p * 128 + ch);
        int c = idx >> 3, w = (idx & 7) << 3;
        int pp = p0 + w;
        rv[j] = make_uint4(0u, 0u, 0u, 0u);
        if ((unsigned)pp < (unsigned)LTOT)
          rv[j] = *reinterpret_cast<const uint4*>(Vp + (size_t)c * LTOT + pp);
      }
    }

    f32x4 e0[4], e1[4];
#pragma unroll
    for (int nt = 0; nt < 4; ++nt) {
      e0[nt] = (f32x4){0.f, 0.f, 0.f, 0.f};
      e1[nt] = (f32x4){0.f, 0.f, 0.f, 0.f};
    }
#pragma unroll
    for (int kc = 0; kc < 4; ++kc) {
      const int ko = kc * 32 + (lg << 3);
#pragma unroll
      for (int nt = 0; nt < 4; ++nt) {
        bf16x8 bk = *reinterpret_cast<const bf16x8*>(&sKT[(nt * 16 + lr) * 136 + ko]);
        e0[nt] = __builtin_amdgcn_mfma_f32_16x16x32_bf16(bk, aQ0[kc], e0[nt], 0, 0, 0);
        e1[nt] = __builtin_amdgcn_mfma_f32_16x16x32_bf16(bk, aQ1[kc], e1[nt], 0, 0, 0);
      }
    }

    const int wbase = it * 64 + (lg << 2);
    f32x4 lf[4], fmv[4];
#pragma unroll
    for (int nt = 0; nt < 4; ++nt) {
      lf[nt]  = *reinterpret_cast<const f32x4*>(&sLF[wbase + nt * 16]);
      fmv[nt] = *reinterpret_cast<const f32x4*>(&sFM[wbase + nt * 16]);
      e0[nt] += lf[nt];
      e1[nt] += lf[nt];
    }

    bf16x8 bpA0, bpA1;
    {
      float lmax = e0[0][0];
#pragma unroll
      for (int nt = 0; nt < 4; ++nt)
#pragma unroll
        for (int r = 0; r < 4; ++r) if (nt || r) lmax = fmaxf(lmax, e0[nt][r]);
      if (__any(lmax > m0 + 12.0f)) {
        float rmax = lmax;
        rmax = fmaxf(rmax, __shfl_xor(rmax, 16));
        rmax = fmaxf(rmax, __shfl_xor(rmax, 32));
        float mnew = fmaxf(m0, rmax);
        float fs = exp2f(m0 - mnew);
        d40 *= fs;
#pragma unroll
        for (int cm = 0; cm < 8; ++cm) accO0[cm] *= fs;
        m0 = mnew;
      }
      f32x4 pn[4];
#pragma unroll
      for (int nt = 0; nt < 4; ++nt) {
        f32x4 pd;
#pragma unroll
        for (int r = 0; r < 4; ++r) pd[r] = exp2f(e0[nt][r] - m0);
        d40 += pd;
        pn[nt] = pd * fmv[nt];
      }
      bpA0 = pack_bp(pn[0], pn[1]);
      bpA1 = pack_bp(pn[2], pn[3]);
    }

    bf16x8 bpB0, bpB1;
    {
      float lmax = e1[0][0];
#pragma unroll
      for (int nt = 0; nt < 4; ++nt)
#pragma unroll
        for (int r = 0; r < 4; ++r) if (nt || r) lmax = fmaxf(lmax, e1[nt][r]);
      if (__any(lmax > m1 + 12.0f)) {
        float rmax = lmax;
        rmax = fmaxf(rmax, __shfl_xor(rmax, 16));
        rmax = fmaxf(rmax, __shfl_xor(rmax, 32));
        float mnew = fmaxf(m1, rmax);
        float fs = exp2f(m1 - mnew);
        d41 *= fs;
#pragma unroll
        for (int cm = 0; cm < 8; ++cm) accO1[cm] *= fs;
        m1 = mnew;
      }
      f32x4 pn[4];
#pragma unroll
      for (int nt = 0; nt < 4; ++nt) {
        f32x4 pd;
#pragma unroll
        for (int r = 0; r < 4; ++r) pd[r] = exp2f(e1[nt][r] - m1);
        d41 += pd;
        pn[nt] = pd * fmv[nt];
      }
      bpB0 = pack_bp(pn[0], pn[1]);
      bpB1 = pack_bp(pn[2], pn[3]);
    }

#pragma unroll
    for (int k2 = 0; k2 < 2; ++k2) {
      const bf16x8 pA = k2 ? bpA1 : bpA0;
      const bf16x8 pB = k2 ? bpB1 : bpB0;
      const int vo = k2 * 32 + (lg << 2);
#pragma unroll
      for (int cm = 0; cm < 8; ++cm) {
        const u16* vr = &sV[(cm * 16 + lr) * 72 + vo];
        bf16x4 v0 = *reinterpret_cast<const bf16x4*>(vr);
        bf16x4 v1 = *reinterpret_cast<const bf16x4*>(vr + 16);
        bf16x8 av = __builtin_shufflevector(v0, v1, 0, 1, 2, 3, 4, 5, 6, 7);
        accO0[cm] = __builtin_amdgcn_mfma_f32_16x16x32_bf16(av, pA, accO0[cm], 0, 0, 0);
        accO1[cm] = __builtin_amdgcn_mfma_f32_16x16x32_bf16(av, pB, accO1[cm], 0, 0, 0);
      }
    }

    __syncthreads();
    if (it < 15) {
#pragma unroll
      for (int j = 0; j < 4; ++j) {
        int idx = tid + j * 256;
        int row = idx >> 4, ch = (idx & 15) << 3;
        *reinterpret_cast<uint4*>(&sKT[row * 136 + ch]) = rk[j];
        int c = idx >> 3, w = (idx & 7) << 3;
        *reinterpret_cast<uint4*>(&sV[c * 72 + w]) = rv[j];
      }
    }
    __syncthreads();
  }

  float ds0 = d40[0] + d40[1] + d40[2] + d40[3];
  ds0 += __shfl_xor(ds0, 16);
  ds0 += __shfl_xor(ds0, 32);
  const float rd0 = 1.f / ds0;
  float ds1 = d41[0] + d41[1] + d41[2] + d41[3];
  ds1 += __shfl_xor(ds1, 16);
  ds1 += __shfl_xor(ds1, 32);
  const float rd1 = 1.f / ds1;

  u16* sT = (u16*)smem + wv * 2176;   // per-wave [16][136]
#pragma unroll
  for (int cm = 0; cm < 8; ++cm) {
    float o0 = fmaxf(accO0[cm][0] * rd0, 0.f);
    float o1 = fmaxf(accO0[cm][1] * rd0, 0.f);
    float o2 = fmaxf(accO0[cm][2] * rd0, 0.f);
    float o3 = fmaxf(accO0[cm][3] * rd0, 0.f);
    uint2 pk = make_uint2(cvt_pk(o0, o1), cvt_pk(o2, o3));
    *reinterpret_cast<uint2*>(&sT[lr * 136 + cm * 16 + (lg << 2)]) = pk;
  }
  for (int idx = lane; idx < 256; idx += 64) {
    int row = idx >> 4, ch = (idx & 15) << 3;
    uint4 v = *reinterpret_cast<const uint4*>(&sT[row * 136 + ch]);
    *reinterpret_cast<uint4*>(attT + (size_t)(wq0 + row) * 128 + ch) = v;
  }
#pragma unroll
  for (int cm = 0; cm < 8; ++cm) {
    float o0 = fmaxf(accO1[cm][0] * rd1, 0.f);
    float o1 = fmaxf(accO1[cm][1] * rd1, 0.f);
    float o2 = fmaxf(accO1[cm][2] * rd1, 0.f);
    float o3 = fmaxf(accO1[cm][3] * rd1, 0.f);
    uint2 pk = make_uint2(cvt_pk(o0, o1), cvt_pk(o2, o3));
    *reinterpret_cast<uint2*>(&sT[lr * 136 + cm * 16 + (lg << 2)]) = pk;
  }
  for (int idx = lane; idx < 256; idx += 64) {
    int row = idx >> 4, ch = (idx & 15) << 3;
    uint4 v = *reinterpret_cast<const uint4*>(&sT[row * 136 + ch]);
    *reinterpret_cast<uint4*>(attT + (size_t)(wq0 + 16 + row) * 128 + ch) = v;
  }
}

// =========================================================================
// Kernel 3: out[o][l] = (WoB @ attT^T + bo) * mask — R10-proven version.
// =========================================================================
__device__ __forceinline__ int sa_addr(int row, int g) {
  return (row << 7) + (((g) ^ (row & 7)) << 3);
}

__global__ __launch_bounds__(512) void k_out(
    const u16* __restrict__ attT, const u16* __restrict__ WoB,
    const float* __restrict__ bo, const float* __restrict__ mask,
    float* __restrict__ out)
{
  __shared__ __align__(16) u16 sA[128 * 128];   // [l][c] swizzled, 32 KiB

  const int tid  = threadIdx.x;
  const int lane = tid & 63;
  const int wv   = tid >> 6;        // 8 waves; wave owns 32 o-rows
  const int lr   = lane & 15;
  const int lg   = lane >> 4;
  const int l0   = blockIdx.x << 7;

  for (int idx = tid; idx < 2048; idx += 512) {
    int row = idx >> 4, g = idx & 15;
    uint4 v = *reinterpret_cast<const uint4*>(attT + (size_t)(l0 + row) * 128 + (g << 3));
    *reinterpret_cast<uint4*>(&sA[sa_addr(row, g)]) = v;
  }
  __syncthreads();

  const int ob = wv << 5;
  f32x4 acc[2][8];
#pragma unroll
  for (int mt = 0; mt < 2; ++mt)
#pragma unroll
    for (int nt = 0; nt < 8; ++nt) acc[mt][nt] = (f32x4){0.f, 0.f, 0.f, 0.f};

#pragma unroll
  for (int kc = 0; kc < 4; ++kc) {
    bf16x8 a[2], b[8];
#pragma unroll
    for (int mt = 0; mt < 2; ++mt)
      a[mt] = *reinterpret_cast<const bf16x8*>(
          WoB + (size_t)(ob + mt * 16 + lr) * 128 + kc * 32 + (lg << 3));
    const int g = (kc << 2) + lg;
#pragma unroll
    for (int nt = 0; nt < 8; ++nt)
      b[nt] = *reinterpret_cast<const bf16x8*>(&sA[sa_addr(nt * 16 + lr, g)]);
#pragma unroll
    for (int mt = 0; mt < 2; ++mt)
#pragma unroll
      for (int nt = 0; nt < 8; ++nt)
        acc[mt][nt] = __builtin_amdgcn_mfma_f32_16x16x32_bf16(a[mt], b[nt], acc[mt][nt], 0, 0, 0);
  }

#pragma unroll
  for (int mt = 0; mt < 2; ++mt) {
    const int o0 = ob + mt * 16 + (lg << 2);
    float4 b4 = *reinterpret_cast<const float4*>(bo + o0);
#pragma unroll
    for (int nt = 0; nt < 8; ++nt) {
      const int l = l0 + nt * 16 + lr;
      const float mk = mask[l];
      out[(size_t)(o0 + 0) * LTOT + l] = (acc[mt][nt][0] + b4.x) * mk;
      out[(size_t)(o0 + 1) * LTOT + l] = (acc[mt][nt][1] + b4.y) * mk;
      out[(size_t)(o0 + 2) * LTOT + l] = (acc[mt][nt][2] + b4.z) * mk;
      out[(size_t)(o0 + 3) * LTOT + l] = (acc[mt][nt][3] + b4.w) * mk;
    }
  }
}

extern "C" void kernel_launch(void* const* d_in, const int* in_sizes, int n_in,
                              void* d_out, int out_size, void* d_ws, size_t ws_size,
                              hipStream_t stream) {
  (void)in_sizes; (void)n_in; (void)out_size; (void)ws_size;
  const float* x1   = (const float*)d_in[0];
  const float* mask = (const float*)d_in[1];
  const float* Wq   = (const float*)d_in[2];
  const float* bq   = (const float*)d_in[3];
  const float* Wk   = (const float*)d_in[4];
  const float* bk   = (const float*)d_in[5];
  const float* Wv   = (const float*)d_in[6];
  const float* bv   = (const float*)d_in[7];
  const float* Wo   = (const float*)d_in[8];
  const float* bo   = (const float*)d_in[9];

  u16* scratch = (u16*)d_out;                // QKV scratch in d_out
  u16* attT    = (u16*)d_ws;                 // 32 MiB
  u16* WB      = attT + (size_t)128 * LTOT;  // +256 KiB weights bf16
  u16* WoB     = WB + 98304;
  float* out   = (float*)d_out;

  hipLaunchKernelGGL(k_prep, dim3(128), dim3(256), 0, stream,
                     Wq, Wk, Wv, Wo, WB);
  hipLaunchKernelGGL(k_qkv, dim3(1024), dim3(512), 0, stream,
                     x1, WB, bq, bk, bv, scratch);
  hipLaunchKernelGGL(k_attn, dim3(1024), dim3(256), 0, stream,
                     scratch, mask, attT);
  hipLaunchKernelGGL(k_out, dim3(1024), dim3(512), 0, stream,
                     attT, WoB, bo, mask, out);
}